// Round 3
// baseline (340.210 us; speedup 1.0000x reference)
//
#include <hip/hip_runtime.h>
#include <cstdint>

// Top-k (k=384) along last axis (C=768) of [B=16, N=4096, C=768] fp32, scatter
// values back, zeros elsewhere. One wave per row, 4 rows per 256-block.
// Binary radix select over monotone uint32 keys using __ballot — ZERO LDS in
// the hot path (R2 showed the DS pipe saturated by LDS-atomic histograms).
// Tie-break = lowest index (matches jax.lax.top_k).

constexpr int C    = 768;
constexpr int TPB  = 256;
constexpr int WPB  = TPB / 64;  // 4 waves (rows) per block
constexpr int EPL  = C / 64;    // 12 elements per lane
constexpr int NV   = EPL / 4;   // 3 float4 loads per lane

__device__ __forceinline__ uint32_t f2key(float f, uint32_t flip) {
    uint32_t b = __float_as_uint(f);
    uint32_t u = (b & 0x80000000u) ? ~b : (b | 0x80000000u); // larger float -> larger u
    return u ^ flip;                                          // flip==~0 for largest=0
}

__global__ __launch_bounds__(TPB) void topk_scatter_row(
        const float* __restrict__ x,
        const int*   __restrict__ pk,
        const int*   __restrict__ plg,
        float*       __restrict__ out,
        int rows) {
    const int lane = threadIdx.x & 63;
    const int wid  = threadIdx.x >> 6;
    const int row  = blockIdx.x * WPB + wid;
    if (row >= rows) return;

    const float* xr   = x   + (size_t)row * C;
    float*       orow = out + (size_t)row * C;

    const int      k    = pk[0];
    const uint32_t flip = (plg[0] != 0) ? 0u : 0xFFFFFFFFu;

    float    v[EPL];
    uint32_t key[EPL];
    // element e = j*4+c lives at row index j*256 + lane*4 + c (coalesced float4)
    #pragma unroll
    for (int j = 0; j < NV; ++j) {
        float4 t = ((const float4*)xr)[j * 64 + lane];
        v[j*4+0] = t.x; v[j*4+1] = t.y; v[j*4+2] = t.z; v[j*4+3] = t.w;
    }
    #pragma unroll
    for (int e = 0; e < EPL; ++e) key[e] = f2key(v[e], flip);

    if (k <= 0) {
        #pragma unroll
        for (int j = 0; j < NV; ++j)
            ((float4*)orow)[j * 64 + lane] = make_float4(0.f, 0.f, 0.f, 0.f);
        return;
    }

    // Binary radix select: find threshold prefix such that exactly k elements
    // have key >= prefix (modulo duplicate ties at full resolution).
    // Invariant: candidates == elements whose key matches `prefix` on bits
    // [31:b+1]; kk = how many of them we still need; candcnt = their count.
    uint32_t prefix  = 0;
    int      kk      = k;
    int      candcnt = C;
    bool     done    = false;

    for (int b = 31; b >= 0; --b) {
        const uint32_t pw  = prefix | (1u << b);
        const uint32_t lim = 1u << b;
        // cnt = # elements with key[31:b] == pw[31:b]  <=>  (key^pw) < 2^b
        int cnt = 0;
        #pragma unroll
        for (int e = 0; e < EPL; ++e)
            cnt += __popcll(__ballot((key[e] ^ pw) < lim));

        if (cnt >= kk) {            // threshold lies in the bit=1 half
            prefix  = pw;
            candcnt = cnt;
            if (cnt == kk) { done = true; break; }
        } else {                    // bit=1 half entirely selected
            kk      -= cnt;
            candcnt -= cnt;
            if (candcnt == kk) { done = true; break; }
        }
    }

    // Rare: duplicates of the exact threshold key straddle the boundary.
    uint32_t selmask = 0;
    if (!done) {
        int base = 0;
        #pragma unroll
        for (int j = 0; j < NV; ++j) {
            int eq[4], le = 0;
            #pragma unroll
            for (int c = 0; c < 4; ++c) { eq[c] = (key[j*4+c] == prefix) ? 1 : 0; le += eq[c]; }
            // exclusive prefix over lanes (index order within a j-slice is lane-major)
            int p = le;
            #pragma unroll
            for (int off = 1; off < 64; off <<= 1) {
                int o = __shfl_up(p, off);
                p += (lane >= off) ? o : 0;
            }
            const int excl = p - le;
            const int tot  = __shfl(p, 63);
            int acc = base + excl;
            #pragma unroll
            for (int c = 0; c < 4; ++c) {
                if (eq[c] && acc < kk) selmask |= 1u << (j*4+c);
                acc += eq[c];
            }
            base += tot;
        }
    }

    #pragma unroll
    for (int j = 0; j < NV; ++j) {
        float4 o;
        float* oo = (float*)&o;
        #pragma unroll
        for (int c = 0; c < 4; ++c) {
            const int e = j*4 + c;
            bool sel = done ? (key[e] >= prefix)
                            : ((key[e] > prefix) || ((selmask >> e) & 1u));
            oo[c] = sel ? v[e] : 0.0f;
        }
        ((float4*)orow)[j * 64 + lane] = o;
    }
}

extern "C" void kernel_launch(void* const* d_in, const int* in_sizes, int n_in,
                              void* d_out, int out_size, void* d_ws, size_t ws_size,
                              hipStream_t stream) {
    const float* x   = (const float*)d_in[0];
    const int*   pk  = (const int*)d_in[1];
    const int*   plg = (const int*)d_in[2];
    float*       out = (float*)d_out;

    const int rows   = in_sizes[0] / C;           // 16*4096 = 65536
    const int blocks = (rows + WPB - 1) / WPB;    // 16384
    topk_scatter_row<<<blocks, TPB, 0, stream>>>(x, pk, plg, out, rows);
}